// Round 13
// baseline (3122.404 us; speedup 1.0000x reference)
//
#include <hip/hip_runtime.h>
#include <hip/hip_bf16.h>

// ---------------- ViT-B/16 forward, MI355X round 13 ----------------
// vs round 12 (2893us):
//  - NEW gemm_tn2: 2-barrier structure, BM=128 x BN=256, 4 waves of 64x128
//    (43.7 FLOP/LDS-byte vs 32 for 64x64 -> LDS-BW ceiling 27% vs 20%),
//    LDS 48KB -> 2 blocks/CU. Used ONLY for qkv: grid 52x9=468 blocks ~=
//    one full round at 2/CU. (mlp1 keeps tn<128>: 1248-block grid already
//    ~5 blocks/CU; gemm8p retired.)
//  - all else identical to round 12 (ln_wconv fusion, tn64 o/mlp2/patch,
//    tn128 mlp1, 4-wave attn, ~117MB L3-resident ws).

typedef __attribute__((ext_vector_type(8))) short short8;
typedef __attribute__((ext_vector_type(4))) float f32x4;
typedef __attribute__((ext_vector_type(4))) unsigned short us4;

#define MFMA16(a, b, c) __builtin_amdgcn_mfma_f32_16x16x32_bf16(a, b, c, 0, 0, 0)

#define BATCH 32
#define SEQ 197
#define SPAD 208          // 13 * 16
#define DIM 768
#define HEADS 12
#define DKH 64
#define MLPD 3072
#define NCLS 1000
#define NPATCH 196
#define PDIM 768
#define QKVD 2304
#define ROWS (BATCH * SPAD)   // 6656 = 52*128 = 104*64
#define WT_ELEMS 7077888      // per-layer bf16 weight region (elems)

static __device__ __forceinline__ unsigned short f2bf(float f) {
    unsigned int u = __builtin_bit_cast(unsigned int, f);
    u += 0x7fffu + ((u >> 16) & 1u);             // RNE
    return (unsigned short)(u >> 16);
}

__device__ __forceinline__ void gload16(const void* g, void* l) {
    __builtin_amdgcn_global_load_lds(
        (const __attribute__((address_space(1))) void*)g,
        (__attribute__((address_space(3))) void*)l, 16, 0, 0);
}

// ---------------- patch extraction: x[B,3,224,224] -> patches bf16 [B,196,768]
__global__ __launch_bounds__(256) void patchify(const float* __restrict__ x,
                                                unsigned short* __restrict__ out) {
    int i = blockIdx.x * 256 + threadIdx.x;
    if (i >= BATCH * NPATCH * PDIM) return;
    int b = i / (NPATCH * PDIM);
    int f = i % (NPATCH * PDIM);
    int c = f / 50176, r = f % 50176;
    int gy = r / 3584, r2 = r % 3584;
    int gx = r2 >> 8, r3 = r2 & 255;
    int py = r3 >> 4, px = r3 & 15;
    float v = x[(((size_t)b * 3 + c) * 224 + gy * 16 + py) * 224 + gx * 16 + px];
    out[i] = f2bf(v);
}

// row 0 (cls + pos) and zero pad rows 197..207 of the fp32 residual stream
__global__ __launch_bounds__(256) void embed_misc(const float* __restrict__ cls,
                                                  const float* __restrict__ pos,
                                                  float* __restrict__ h) {
    int b = blockIdx.x, t = threadIdx.x;
    float* hb = h + (size_t)b * SPAD * DIM;
    for (int d = t; d < DIM; d += 256) hb[d] = cls[d] + pos[d];
    for (int i = t; i < (SPAD - SEQ) * DIM; i += 256) hb[SEQ * DIM + i] = 0.f;
}

// ---------------- transpose-convert: src fp32 [K,N] -> dst bf16 [N,K] (32x32 tiles)
__global__ __launch_bounds__(256) void tconv(const float* __restrict__ src,
                                             unsigned short* __restrict__ dst,
                                             int K, int N) {
    __shared__ float tile[32][33];
    int tn = blockIdx.x, tk = blockIdx.y;
    int t = threadIdx.x, r = t >> 3, c4 = (t & 7) << 2;
    float4 v = *reinterpret_cast<const float4*>(&src[(size_t)(tk * 32 + r) * N + tn * 32 + c4]);
    tile[r][c4 + 0] = v.x; tile[r][c4 + 1] = v.y;
    tile[r][c4 + 2] = v.z; tile[r][c4 + 3] = v.w;
    __syncthreads();
    us4 o = { f2bf(tile[c4 + 0][r]), f2bf(tile[c4 + 1][r]),
              f2bf(tile[c4 + 2][r]), f2bf(tile[c4 + 3][r]) };
    *reinterpret_cast<us4*>(&dst[(size_t)(tn * 32 + r) * K + tk * 32 + c4]) = o;
}

// headW fp32 [768,1000] -> hwT bf16 [1024,768], cols >=1000 zero
__global__ __launch_bounds__(256) void hconv(const float* __restrict__ src,
                                             unsigned short* __restrict__ dst) {
    __shared__ float tile[32][33];
    int tn = blockIdx.x, tk = blockIdx.y;
    int t = threadIdx.x, r = t >> 3, c4 = (t & 7) << 2;
#pragma unroll
    for (int i = 0; i < 4; ++i) {
        int c = tn * 32 + c4 + i;
        tile[r][c4 + i] = (c < NCLS) ? src[(size_t)(tk * 32 + r) * NCLS + c] : 0.f;
    }
    __syncthreads();
    us4 o = { f2bf(tile[c4 + 0][r]), f2bf(tile[c4 + 1][r]),
              f2bf(tile[c4 + 2][r]), f2bf(tile[c4 + 3][r]) };
    *reinterpret_cast<us4*>(&dst[(size_t)(tn * 32 + r) * 768 + tk * 32 + c4]) = o;
}

// ---------------- FUSED: per-layer weight conversion + LN1.
__global__ __launch_bounds__(256) void ln_wconv(
    const float* __restrict__ q, const float* __restrict__ k,
    const float* __restrict__ v, const float* __restrict__ o,
    const float* __restrict__ w1, const float* __restrict__ w2,
    unsigned short* __restrict__ wT,
    const float* __restrict__ x, const float* __restrict__ g,
    const float* __restrict__ b, unsigned short* __restrict__ y) {
    if (blockIdx.x < 6912) {
        __shared__ float tile[32][33];
        int tb = blockIdx.x;
        const float* src; unsigned short* dst; int K, N;
        if (tb < 2304) {
            K = 768; N = 768;
            int m = tb / 576; tb -= m * 576;
            src = (m == 0) ? q : (m == 1) ? k : (m == 2) ? v : o;
            dst = wT + (m < 3 ? (size_t)m * 589824 : (size_t)1769472);
        } else if (tb < 4608) {
            tb -= 2304; K = 768; N = 3072; src = w1; dst = wT + 2359296;
        } else {
            tb -= 4608; K = 3072; N = 768; src = w2; dst = wT + 4718592;
        }
        int TN = N >> 5;
        int tn = tb % TN, tk = tb / TN;
        int t = threadIdx.x, r = t >> 3, c4 = (t & 7) << 2;
        float4 vv = *reinterpret_cast<const float4*>(
            &src[(size_t)(tk * 32 + r) * N + tn * 32 + c4]);
        tile[r][c4 + 0] = vv.x; tile[r][c4 + 1] = vv.y;
        tile[r][c4 + 2] = vv.z; tile[r][c4 + 3] = vv.w;
        __syncthreads();
        us4 ov = { f2bf(tile[c4 + 0][r]), f2bf(tile[c4 + 1][r]),
                   f2bf(tile[c4 + 2][r]), f2bf(tile[c4 + 3][r]) };
        *reinterpret_cast<us4*>(&dst[(size_t)(tn * 32 + r) * K + tk * 32 + c4]) = ov;
    } else {
        __shared__ float red[8];
        int row = blockIdx.x - 6912, t = threadIdx.x;
        const float* xr = x + (size_t)row * DIM;
        float v0 = xr[t], v1 = xr[t + 256], v2 = xr[t + 512];
        float s = v0 + v1 + v2, sq = v0 * v0 + v1 * v1 + v2 * v2;
#pragma unroll
        for (int off = 1; off < 64; off <<= 1) {
            s += __shfl_xor(s, off);
            sq += __shfl_xor(sq, off);
        }
        if ((t & 63) == 0) { red[t >> 6] = s; red[4 + (t >> 6)] = sq; }
        __syncthreads();
        s = red[0] + red[1] + red[2] + red[3];
        sq = red[4] + red[5] + red[6] + red[7];
        float mu = s * (1.f / 768.f);
        float var = fmaxf(sq * (1.f / 768.f) - mu * mu, 0.f);
        float rs = rsqrtf(var + 1e-5f);
        unsigned short* yr = y + (size_t)row * DIM;
        yr[t]       = f2bf((v0 - mu) * rs * g[t] + b[t]);
        yr[t + 256] = f2bf((v1 - mu) * rs * g[t + 256] + b[t + 256]);
        yr[t + 512] = f2bf((v2 - mu) * rs * g[t + 512] + b[t + 512]);
    }
}

// pack per-layer qkv bias: bqkv[12][2304]
__global__ __launch_bounds__(256) void pack_bias(const float* __restrict__ bq,
                                                 const float* __restrict__ bk,
                                                 const float* __restrict__ bv,
                                                 float* __restrict__ dst) {
    int i = blockIdx.x * 256 + threadIdx.x;
    if (i >= 12 * QKVD) return;
    int l = i / QKVD, c = i % QKVD;
    float v = (c < 768) ? bq[l * 768 + c]
            : (c < 1536) ? bk[l * 768 + c - 768]
                         : bv[l * 768 + c - 1536];
    dst[i] = v;
}

// ---------------- gemm_tn2: C = A@Bt^T + bias (bf16 out). 2-barrier, BM=128,
// BN=256, BK=64, 4 waves of 64x128 (acc[4][8]). 48KB LDS -> 2 blocks/CU.
// Per wave per K-tile: 8 A + 16 B = 24 ds_read_b128 for 1.05M FLOP.
__global__ __launch_bounds__(256) void gemm_tn2(
    const unsigned short* __restrict__ A, const unsigned short* __restrict__ Bt,
    const float* __restrict__ bias, int N, int K,
    unsigned short* __restrict__ outb) {
    constexpr int CPW = 12;               // (16 A + 32 B chunks)/4 waves
    __shared__ unsigned short Alds[128 * 64];   // 16KB
    __shared__ unsigned short Blds[256 * 64];   // 32KB
    const int tid = threadIdx.x, lane = tid & 63, wid = tid >> 6;
    const int row0 = blockIdx.x * 128, col0 = blockIdx.y * 256;
    const int wm = (wid >> 1) * 64, wn = (wid & 1) * 128;
    const int lr = lane & 15, lg = lane >> 4;
    const int ric = lane >> 3;
    const int sswz = (lane & 7) ^ ric;

    const char* gptr[CPW];
    char* lptr[CPW];
#pragma unroll
    for (int j = 0; j < CPW; ++j) {
        int cc = wid * CPW + j;
        if (cc < 16) {
            int grow = row0 + cc * 8 + ric;
            gptr[j] = (const char*)A + (size_t)grow * K * 2 + sswz * 16;
            lptr[j] = (char*)Alds + cc * 1024;
        } else {
            int grow = col0 + (cc - 16) * 8 + ric;
            gptr[j] = (const char*)Bt + (size_t)grow * K * 2 + sswz * 16;
            lptr[j] = (char*)Blds + (cc - 16) * 1024;
        }
    }

    f32x4 acc[4][8];
#pragma unroll
    for (int m = 0; m < 4; ++m)
#pragma unroll
        for (int n = 0; n < 8; ++n) acc[m][n] = (f32x4){0.f, 0.f, 0.f, 0.f};

    const int rsw = lr & 7;
    for (int ks = 0; ks < K; ks += 64) {
        __syncthreads();
#pragma unroll
        for (int j = 0; j < CPW; ++j) {
            gload16(gptr[j], lptr[j]);
            gptr[j] += 128;
        }
        __syncthreads();
        short8 af[4][2];
#pragma unroll
        for (int m = 0; m < 4; ++m)
#pragma unroll
            for (int kk = 0; kk < 2; ++kk)
                af[m][kk] = *reinterpret_cast<const short8*>(
                    &Alds[(wm + m * 16 + lr) * 64 + (((kk * 4 + lg) ^ rsw) << 3)]);
#pragma unroll
        for (int n = 0; n < 8; ++n) {
            short8 b0 = *reinterpret_cast<const short8*>(
                &Blds[(wn + n * 16 + lr) * 64 + ((lg ^ rsw) << 3)]);
            short8 b1 = *reinterpret_cast<const short8*>(
                &Blds[(wn + n * 16 + lr) * 64 + (((4 + lg) ^ rsw) << 3)]);
#pragma unroll
            for (int m = 0; m < 4; ++m) {
                acc[m][n] = MFMA16(af[m][0], b0, acc[m][n]);
                acc[m][n] = MFMA16(af[m][1], b1, acc[m][n]);
            }
        }
    }
#pragma unroll
    for (int m = 0; m < 4; ++m) {
#pragma unroll
        for (int n = 0; n < 8; ++n) {
            int gcol = col0 + wn + n * 16 + lr;
            float bv = bias[gcol];
#pragma unroll
            for (int i = 0; i < 4; ++i) {
                int grow = row0 + wm + m * 16 + lg * 4 + i;
                outb[(size_t)grow * N + gcol] = f2bf(acc[m][n][i] + bv);
            }
        }
    }
}

// ---------------- round-3 2-barrier GEMM (proven best for short-K grids)
// mode 0: bf16 out  1: outf += (residual)  2: gelu->bf16  3: patch embed(+pos)
// mode 4: head fp32 out guarded to [32,NCLS], bias via pos ptr
template <int BM>
__global__ __launch_bounds__(256) void gemm_tn(
    const unsigned short* __restrict__ A, const unsigned short* __restrict__ Bt,
    const float* __restrict__ bias, int M, int N, int K, int mode,
    unsigned short* __restrict__ outb, float* __restrict__ outf,
    const float* __restrict__ pos) {
    constexpr int MFRAG = BM / 32;
    constexpr int ACH = BM / 8;
    constexpr int TOT = ACH + 16;
    constexpr int CPW = TOT / 4;
    __shared__ unsigned short Alds[BM * 64];
    __shared__ unsigned short Blds[128 * 64];
    const int tid = threadIdx.x, lane = tid & 63, wid = tid >> 6;
    const int row0 = blockIdx.x * BM, col0 = blockIdx.y * 128;
    const int wm = (wid >> 1) * (BM / 2), wn = (wid & 1) * 64;
    const int lr = lane & 15, lg = lane >> 4;
    const int ric = lane >> 3;
    const int sswz = (lane & 7) ^ ric;

    const char* gptr[CPW];
    char* lptr[CPW];
#pragma unroll
    for (int j = 0; j < CPW; ++j) {
        int cc = wid * CPW + j;
        if (cc < ACH) {
            int grow = row0 + cc * 8 + ric;
            gptr[j] = (const char*)A + (size_t)grow * K * 2 + sswz * 16;
            lptr[j] = (char*)Alds + cc * 1024;
        } else {
            int grow = col0 + (cc - ACH) * 8 + ric;
            gptr[j] = (const char*)Bt + (size_t)grow * K * 2 + sswz * 16;
            lptr[j] = (char*)Blds + (cc - ACH) * 1024;
        }
    }

    f32x4 acc[MFRAG][4];
#pragma unroll
    for (int m = 0; m < MFRAG; ++m)
#pragma unroll
        for (int n = 0; n < 4; ++n) acc[m][n] = (f32x4){0.f, 0.f, 0.f, 0.f};

    const int rsw = lr & 7;
    for (int ks = 0; ks < K; ks += 64) {
        __syncthreads();
#pragma unroll
        for (int j = 0; j < CPW; ++j) {
            gload16(gptr[j], lptr[j]);
            gptr[j] += 128;
        }
        __syncthreads();
        short8 af[MFRAG][2], bfr[4][2];
#pragma unroll
        for (int m = 0; m < MFRAG; ++m)
#pragma unroll
            for (int kk = 0; kk < 2; ++kk)
                af[m][kk] = *reinterpret_cast<const short8*>(
                    &Alds[(wm + m * 16 + lr) * 64 + (((kk * 4 + lg) ^ rsw) << 3)]);
#pragma unroll
        for (int n = 0; n < 4; ++n)
#pragma unroll
            for (int kk = 0; kk < 2; ++kk)
                bfr[n][kk] = *reinterpret_cast<const short8*>(
                    &Blds[(wn + n * 16 + lr) * 64 + (((kk * 4 + lg) ^ rsw) << 3)]);
#pragma unroll
        for (int m = 0; m < MFRAG; ++m)
#pragma unroll
            for (int n = 0; n < 4; ++n) {
                acc[m][n] = MFMA16(af[m][0], bfr[n][0], acc[m][n]);
                acc[m][n] = MFMA16(af[m][1], bfr[n][1], acc[m][n]);
            }
    }
#pragma unroll
    for (int m = 0; m < MFRAG; ++m) {
#pragma unroll
        for (int n = 0; n < 4; ++n) {
            int gcol = col0 + wn + n * 16 + lr;
            float bv = bias ? bias[gcol] : 0.f;
#pragma unroll
            for (int i = 0; i < 4; ++i) {
                int grow = row0 + wm + m * 16 + lg * 4 + i;
                float v = acc[m][n][i] + bv;
                if (mode == 0) {
                    outb[(size_t)grow * N + gcol] = f2bf(v);
                } else if (mode == 1) {
                    outf[(size_t)grow * N + gcol] += v;
                } else if (mode == 2) {
                    v = 0.5f * v * (1.f + erff(v * 0.70710678118654752f));
                    outb[(size_t)grow * N + gcol] = f2bf(v);
                } else if (mode == 3) {
                    int pb = grow / NPATCH, pn = grow % NPATCH;
                    size_t o = ((size_t)pb * SPAD + 1 + pn) * DIM + gcol;
                    outf[o] = v + pos[(size_t)(1 + pn) * DIM + gcol];
                } else {
                    if (grow < BATCH && gcol < NCLS)
                        outf[(size_t)grow * NCLS + gcol] = v + pos[gcol];
                }
            }
        }
    }
}

// ---------------- LayerNorm fp32 -> bf16, one block per row (D=768)
__global__ __launch_bounds__(256) void ln_bf16(const float* __restrict__ x,
                                               const float* __restrict__ g,
                                               const float* __restrict__ b,
                                               unsigned short* __restrict__ y) {
    __shared__ float red[8];
    int row = blockIdx.x, t = threadIdx.x;
    const float* xr = x + (size_t)row * DIM;
    float v0 = xr[t], v1 = xr[t + 256], v2 = xr[t + 512];
    float s = v0 + v1 + v2, sq = v0 * v0 + v1 * v1 + v2 * v2;
#pragma unroll
    for (int off = 1; off < 64; off <<= 1) {
        s += __shfl_xor(s, off);
        sq += __shfl_xor(sq, off);
    }
    if ((t & 63) == 0) { red[t >> 6] = s; red[4 + (t >> 6)] = sq; }
    __syncthreads();
    s = red[0] + red[1] + red[2] + red[3];
    sq = red[4] + red[5] + red[6] + red[7];
    float mu = s * (1.f / 768.f);
    float var = fmaxf(sq * (1.f / 768.f) - mu * mu, 0.f);
    float rs = rsqrtf(var + 1e-5f);
    unsigned short* yr = y + (size_t)row * DIM;
    yr[t]       = f2bf((v0 - mu) * rs * g[t] + b[t]);
    yr[t + 256] = f2bf((v1 - mu) * rs * g[t + 256] + b[t + 256]);
    yr[t + 512] = f2bf((v2 - mu) * rs * g[t + 512] + b[t + 512]);
}

// LN of cls rows only -> clsbuf bf16 [64][768] (rows 32..63 zero)
__global__ __launch_bounds__(256) void ln_cls(const float* __restrict__ x,
                                              const float* __restrict__ g,
                                              const float* __restrict__ b,
                                              unsigned short* __restrict__ y) {
    __shared__ float red[8];
    int bb = blockIdx.x, t = threadIdx.x;
    unsigned short* yr = y + (size_t)bb * DIM;
    if (bb >= BATCH) {
        yr[t] = 0; yr[t + 256] = 0; yr[t + 512] = 0;
        return;
    }
    const float* xr = x + (size_t)bb * SPAD * DIM;
    float v0 = xr[t], v1 = xr[t + 256], v2 = xr[t + 512];
    float s = v0 + v1 + v2, sq = v0 * v0 + v1 * v1 + v2 * v2;
#pragma unroll
    for (int off = 1; off < 64; off <<= 1) {
        s += __shfl_xor(s, off);
        sq += __shfl_xor(sq, off);
    }
    if ((t & 63) == 0) { red[t >> 6] = s; red[4 + (t >> 6)] = sq; }
    __syncthreads();
    s = red[0] + red[1] + red[2] + red[3];
    sq = red[4] + red[5] + red[6] + red[7];
    float mu = s * (1.f / 768.f);
    float var = fmaxf(sq * (1.f / 768.f) - mu * mu, 0.f);
    float rs = rsqrtf(var + 1e-5f);
    yr[t]       = f2bf((v0 - mu) * rs * g[t] + b[t]);
    yr[t + 256] = f2bf((v1 - mu) * rs * g[t + 256] + b[t + 256]);
    yr[t + 512] = f2bf((v2 - mu) * rs * g[t + 512] + b[t + 512]);
}

// ---------------- fused attention: per (h,b) block, 4 waves (round-6, proven)
__global__ __launch_bounds__(256) void attn_fused(const unsigned short* __restrict__ qkv,
                                                  unsigned short* __restrict__ att) {
    __shared__ unsigned short Klds[26 * 512];
    __shared__ unsigned short Vlds[64][232];
    __shared__ unsigned short Plds[4][16 * 256];
    int h = blockIdx.x, b = blockIdx.y, tid = threadIdx.x;
    int wid = tid >> 6, lane = tid & 63, lr = lane & 15, lg = lane >> 4;
    const int ric = lane >> 3, sswz = (lane & 7) ^ ric;

    const char* pK = (const char*)qkv +
        ((size_t)(b * SPAD + ric) * QKVD + 768 + h * DKH) * 2 + sswz * 16;
    for (int c = wid; c < 26; c += 4)
        gload16(pK + (size_t)c * 8 * QKVD * 2, (char*)Klds + c * 1024);

    for (int idx = tid; idx < SPAD * 8; idx += 256) {
        int s = idx >> 3, dc = (idx & 7) << 3;
        uint4 w = *reinterpret_cast<const uint4*>(
            &qkv[((size_t)b * SPAD + s) * QKVD + 1536 + h * DKH + dc]);
        const unsigned short* pe = reinterpret_cast<const unsigned short*>(&w);
#pragma unroll
        for (int i = 0; i < 8; ++i) Vlds[dc + i][s] = pe[i];
    }
    for (int i = tid; i < 64 * 24; i += 256) Vlds[i / 24][208 + (i % 24)] = 0;
    __syncthreads();

    unsigned short* Pw = &Plds[wid][0];
    const short8 zero8 = {0, 0, 0, 0, 0, 0, 0, 0};
    const int rowin = lr & 7;

    for (int qt = wid; qt < 13; qt += 4) {
        size_t qoff = ((size_t)b * SPAD + qt * 16 + lr) * QKVD + h * DKH + lg * 8;
        short8 qf0 = *reinterpret_cast<const short8*>(&qkv[qoff]);
        short8 qf1 = *reinterpret_cast<const short8*>(&qkv[qoff + 32]);
        f32x4 acc[13];
#pragma unroll
        for (int kt = 0; kt < 13; ++kt) {
            const unsigned short* kbase = Klds + (kt * 2 + (lr >> 3)) * 512 + rowin * 64;
            short8 kf0 = *reinterpret_cast<const short8*>(&kbase[(lg ^ rowin) << 3]);
            short8 kf1 = *reinterpret_cast<const short8*>(&kbase[((4 + lg) ^ rowin) << 3]);
            f32x4 a = (f32x4){0.f, 0.f, 0.f, 0.f};
            a = MFMA16(qf0, kf0, a);
            a = MFMA16(qf1, kf1, a);
            acc[kt] = a;
        }
#pragma unroll
        for (int kt = 0; kt < 13; ++kt)
#pragma unroll
            for (int r = 0; r < 4; ++r) acc[kt][r] *= 0.125f;
        if (lr >= 5) {
#pragma unroll
            for (int r = 0; r < 4; ++r) acc[12][r] = -1e30f;   // tokens >=197
        }
        float mx[4] = {-1e30f, -1e30f, -1e30f, -1e30f};
#pragma unroll
        for (int kt = 0; kt < 13; ++kt)
#pragma unroll
            for (int r = 0; r < 4; ++r) mx[r] = fmaxf(mx[r], acc[kt][r]);
#pragma unroll
        for (int r = 0; r < 4; ++r) {
            mx[r] = fmaxf(mx[r], __shfl_xor(mx[r], 1));
            mx[r] = fmaxf(mx[r], __shfl_xor(mx[r], 2));
            mx[r] = fmaxf(mx[r], __shfl_xor(mx[r], 4));
            mx[r] = fmaxf(mx[r], __shfl_xor(mx[r], 8));
        }
        float sm[4] = {0.f, 0.f, 0.f, 0.f};
#pragma unroll
        for (int kt = 0; kt < 13; ++kt)
#pragma unroll
            for (int r = 0; r < 4; ++r) {
                float e = __expf(acc[kt][r] - mx[r]);
                acc[kt][r] = e;
                sm[r] += e;
            }
#pragma unroll
        for (int r = 0; r < 4; ++r) {
            sm[r] += __shfl_xor(sm[r], 1);
            sm[r] += __shfl_xor(sm[r], 2);
            sm[r] += __shfl_xor(sm[r], 4);
            sm[r] += __shfl_xor(sm[r], 8);
        }
#pragma unroll
        for (int r = 0; r < 4; ++r) {
            int row = lg * 4 + r;
            float inv = 1.f / sm[r];
#pragma unroll
            for (int kt = 0; kt < 13; ++kt) {
                int col = kt * 16 + lr;
                int idx = row * 256 + ((((col >> 3) ^ (row & 7)) << 3) | (col & 7));
                Pw[idx] = f2bf(acc[kt][r] * inv);
            }
        }
        if (lr < 6) {
            int s = 26 + lr;
#pragma unroll
            for (int r = 0; r < 4; ++r) {
                int row = lg * 4 + r;
                *reinterpret_cast<short8*>(&Pw[row * 256 + ((s ^ (row & 7)) << 3)]) = zero8;
            }
        }
        int rsw = lr & 7;
#pragma unroll
        for (int dt = 0; dt < 4; ++dt) {
            f32x4 a = (f32x4){0.f, 0.f, 0.f, 0.f};
#pragma unroll
            for (int kk = 0; kk < 7; ++kk) {
                short8 af = *reinterpret_cast<const short8*>(
                    &Pw[lr * 256 + (((kk * 4 + lg) ^ rsw) << 3)]);
                short8 bfr = *reinterpret_cast<const short8*>(
                    &Vlds[dt * 16 + lr][kk * 32 + lg * 8]);
                a = MFMA16(af, bfr, a);
            }
#pragma unroll
            for (int i = 0; i < 4; ++i) {
                int s = qt * 16 + lg * 4 + i;
                att[((size_t)b * SPAD + s) * DIM + h * DKH + dt * 16 + lr] = f2bf(a[i]);
            }
        }
    }
}

extern "C" void kernel_launch(void* const* d_in, const int* in_sizes, int n_in,
                              void* d_out, int out_size, void* d_ws, size_t ws_size,
                              hipStream_t stream) {
    const float* x      = (const float*)d_in[0];
    const float* patchW = (const float*)d_in[1];
    const float* patchB = (const float*)d_in[2];
    const float* clstok = (const float*)d_in[3];
    const float* pose   = (const float*)d_in[4];
    const float* Wq = (const float*)d_in[5];
    const float* bq = (const float*)d_in[6];
    const float* Wk = (const float*)d_in[7];
    const float* bk = (const float*)d_in[8];
    const float* Wv = (const float*)d_in[9];
    const float* bv = (const float*)d_in[10];
    const float* Wo = (const float*)d_in[11];
    const float* bo = (const float*)d_in[12];
    const float* ln1g = (const float*)d_in[13];
    const float* ln1b = (const float*)d_in[14];
    const float* ln2g = (const float*)d_in[15];
    const float* ln2b = (const float*)d_in[16];
    const float* W1 = (const float*)d_in[17];
    const float* b1 = (const float*)d_in[18];
    const float* W2 = (const float*)d_in[19];
    const float* b2 = (const float*)d_in[20];
    const float* lnpg = (const float*)d_in[21];
    const float* lnpb = (const float*)d_in[22];
    const float* headW = (const float*)d_in[23];
    const float* headB = (const float*)d_in[24];
    float* out = (float*)d_out;

    // ws footprint ~117MB -> working set stays L3-resident (round-9 lesson).
    constexpr size_t SZ_H   = (size_t)ROWS * DIM * 4;
    constexpr size_t SZ_QKV = (size_t)ROWS * QKVD * 2;
    constexpr size_t SZ_Y   = (size_t)ROWS * DIM * 2;
    constexpr size_t SZ_M1  = (size_t)ROWS * MLPD * 2;
    constexpr size_t SZ_WT  = (size_t)WT_ELEMS * 2;
    char* w = (char*)d_ws;
    float* hbuf            = (float*)w;
    unsigned short* qkvb   = (unsigned short*)(w + SZ_H);
    unsigned short* ybuf   = (unsigned short*)(w + SZ_H + SZ_QKV);
    unsigned short* m1buf  = (unsigned short*)(w + SZ_H + SZ_QKV + SZ_Y);
    unsigned short* wT     = (unsigned short*)(w + SZ_H + SZ_QKV + SZ_Y + SZ_M1);
    float* bqkv            = (float*)(w + SZ_H + SZ_QKV + SZ_Y + SZ_M1 + SZ_WT);
    unsigned short* patches = m1buf;          // embed phase (4.8M elems @ m1buf)
    unsigned short* pwT     = ybuf;           // patch weightT scratch (ybuf idle
                                              // until layer-0 LN)
    unsigned short* clsbuf  = m1buf;          // head phase [64][768]
    unsigned short* hwT     = m1buf + 64 * DIM;  // head phase [1024][768]

    pack_bias<<<dim3(108), 256, 0, stream>>>(bq, bk, bv, bqkv);

    // patch embed (patches in m1buf, weightsT in ybuf — disjoint)
    tconv<<<dim3(24, 24), 256, 0, stream>>>(patchW, pwT, PDIM, DIM);
    patchify<<<dim3((BATCH * NPATCH * PDIM + 255) / 256), 256, 0, stream>>>(x, patches);
    embed_misc<<<dim3(BATCH), 256, 0, stream>>>(clstok, pose, hbuf);
    gemm_tn<64><<<dim3(98, 6), 256, 0, stream>>>(patches, pwT, patchB,
                                                 BATCH * NPATCH, DIM, PDIM, 3,
                                                 nullptr, hbuf, pose);

    for (int i = 0; i < 12; ++i) {
        // fused: weight conversion (blocks 0..6911) + LN1 (blocks 6912..13567)
        ln_wconv<<<dim3(6912 + ROWS), 256, 0, stream>>>(
            Wq + (size_t)i * DIM * DIM, Wk + (size_t)i * DIM * DIM,
            Wv + (size_t)i * DIM * DIM, Wo + (size_t)i * DIM * DIM,
            W1 + (size_t)i * DIM * MLPD, W2 + (size_t)i * DIM * MLPD, wT,
            hbuf, ln1g + i * DIM, ln1b + i * DIM, ybuf);
        gemm_tn2<<<dim3(52, 9), 256, 0, stream>>>(ybuf, wT, bqkv + i * QKVD,
                                                  QKVD, DIM, qkvb);
        attn_fused<<<dim3(HEADS, BATCH), 256, 0, stream>>>(qkvb, ybuf);
        gemm_tn<64><<<dim3(104, 6), 256, 0, stream>>>(ybuf, wT + 1769472, bo + i * DIM,
                                                      ROWS, DIM, DIM, 1,
                                                      nullptr, hbuf, nullptr);
        ln_bf16<<<dim3(ROWS), 256, 0, stream>>>(hbuf, ln2g + i * DIM, ln2b + i * DIM, ybuf);
        gemm_tn<128><<<dim3(52, 24), 256, 0, stream>>>(ybuf, wT + 2359296, b1 + i * MLPD,
                                                       ROWS, MLPD, DIM, 2,
                                                       m1buf, nullptr, nullptr);
        gemm_tn<64><<<dim3(104, 6), 256, 0, stream>>>(m1buf, wT + 4718592, b2 + i * DIM,
                                                      ROWS, DIM, MLPD, 1,
                                                      nullptr, hbuf, nullptr);
    }
    // head: LN cls rows -> clsbuf [64][768]; headW -> hwT [1024][768]; MFMA GEMM
    ln_cls<<<dim3(64), 256, 0, stream>>>(hbuf, lnpg, lnpb, clsbuf);
    hconv<<<dim3(32, 24), 256, 0, stream>>>(headW, hwT);
    gemm_tn<64><<<dim3(1, 8), 256, 0, stream>>>(clsbuf, hwT, nullptr,
                                                64, 1024, DIM, 4,
                                                nullptr, out, headB);
}

// Round 14
// 2755.614 us; speedup vs baseline: 1.1331x; 1.1331x over previous
//
#include <hip/hip_runtime.h>
#include <hip/hip_bf16.h>

// ---------------- ViT-B/16 forward, MI355X round 14 ----------------
// Round-13 lesson: gemm_tn2 (64x128/wave) lost ~19us/layer on qkv to VGPR
// pressure — 4th failed structure variant; round-12 config is the proven
// local optimum. REVERT qkv to gemm8p.
// ONE isolated change vs round 12 (2893us): attn_fused 4 -> 8 waves
// (field-tested in r11, correct absmax; latency-bound at 1 block/CU, so
// doubling waves/CU is the remaining parallelism lever).

typedef __attribute__((ext_vector_type(8))) short short8;
typedef __attribute__((ext_vector_type(4))) float f32x4;
typedef __attribute__((ext_vector_type(4))) unsigned short us4;

#define MFMA16(a, b, c) __builtin_amdgcn_mfma_f32_16x16x32_bf16(a, b, c, 0, 0, 0)

#define BATCH 32
#define SEQ 197
#define SPAD 208          // 13 * 16
#define DIM 768
#define HEADS 12
#define DKH 64
#define MLPD 3072
#define NCLS 1000
#define NPATCH 196
#define PDIM 768
#define QKVD 2304
#define ROWS (BATCH * SPAD)   // 6656 = 52*128 = 104*64
#define WT_ELEMS 7077888      // per-layer bf16 weight region (elems)

static __device__ __forceinline__ unsigned short f2bf(float f) {
    unsigned int u = __builtin_bit_cast(unsigned int, f);
    u += 0x7fffu + ((u >> 16) & 1u);             // RNE
    return (unsigned short)(u >> 16);
}

__device__ __forceinline__ void gload16(const void* g, void* l) {
    __builtin_amdgcn_global_load_lds(
        (const __attribute__((address_space(1))) void*)g,
        (__attribute__((address_space(3))) void*)l, 16, 0, 0);
}

// ---------------- patch extraction: x[B,3,224,224] -> patches bf16 [B,196,768]
__global__ __launch_bounds__(256) void patchify(const float* __restrict__ x,
                                                unsigned short* __restrict__ out) {
    int i = blockIdx.x * 256 + threadIdx.x;
    if (i >= BATCH * NPATCH * PDIM) return;
    int b = i / (NPATCH * PDIM);
    int f = i % (NPATCH * PDIM);
    int c = f / 50176, r = f % 50176;
    int gy = r / 3584, r2 = r % 3584;
    int gx = r2 >> 8, r3 = r2 & 255;
    int py = r3 >> 4, px = r3 & 15;
    float v = x[(((size_t)b * 3 + c) * 224 + gy * 16 + py) * 224 + gx * 16 + px];
    out[i] = f2bf(v);
}

// row 0 (cls + pos) and zero pad rows 197..207 of the fp32 residual stream
__global__ __launch_bounds__(256) void embed_misc(const float* __restrict__ cls,
                                                  const float* __restrict__ pos,
                                                  float* __restrict__ h) {
    int b = blockIdx.x, t = threadIdx.x;
    float* hb = h + (size_t)b * SPAD * DIM;
    for (int d = t; d < DIM; d += 256) hb[d] = cls[d] + pos[d];
    for (int i = t; i < (SPAD - SEQ) * DIM; i += 256) hb[SEQ * DIM + i] = 0.f;
}

// ---------------- transpose-convert: src fp32 [K,N] -> dst bf16 [N,K] (32x32 tiles)
__global__ __launch_bounds__(256) void tconv(const float* __restrict__ src,
                                             unsigned short* __restrict__ dst,
                                             int K, int N) {
    __shared__ float tile[32][33];
    int tn = blockIdx.x, tk = blockIdx.y;
    int t = threadIdx.x, r = t >> 3, c4 = (t & 7) << 2;
    float4 v = *reinterpret_cast<const float4*>(&src[(size_t)(tk * 32 + r) * N + tn * 32 + c4]);
    tile[r][c4 + 0] = v.x; tile[r][c4 + 1] = v.y;
    tile[r][c4 + 2] = v.z; tile[r][c4 + 3] = v.w;
    __syncthreads();
    us4 o = { f2bf(tile[c4 + 0][r]), f2bf(tile[c4 + 1][r]),
              f2bf(tile[c4 + 2][r]), f2bf(tile[c4 + 3][r]) };
    *reinterpret_cast<us4*>(&dst[(size_t)(tn * 32 + r) * K + tk * 32 + c4]) = o;
}

// headW fp32 [768,1000] -> hwT bf16 [1024,768], cols >=1000 zero
__global__ __launch_bounds__(256) void hconv(const float* __restrict__ src,
                                             unsigned short* __restrict__ dst) {
    __shared__ float tile[32][33];
    int tn = blockIdx.x, tk = blockIdx.y;
    int t = threadIdx.x, r = t >> 3, c4 = (t & 7) << 2;
#pragma unroll
    for (int i = 0; i < 4; ++i) {
        int c = tn * 32 + c4 + i;
        tile[r][c4 + i] = (c < NCLS) ? src[(size_t)(tk * 32 + r) * NCLS + c] : 0.f;
    }
    __syncthreads();
    us4 o = { f2bf(tile[c4 + 0][r]), f2bf(tile[c4 + 1][r]),
              f2bf(tile[c4 + 2][r]), f2bf(tile[c4 + 3][r]) };
    *reinterpret_cast<us4*>(&dst[(size_t)(tn * 32 + r) * 768 + tk * 32 + c4]) = o;
}

// ---------------- FUSED: per-layer weight conversion + LN1.
__global__ __launch_bounds__(256) void ln_wconv(
    const float* __restrict__ q, const float* __restrict__ k,
    const float* __restrict__ v, const float* __restrict__ o,
    const float* __restrict__ w1, const float* __restrict__ w2,
    unsigned short* __restrict__ wT,
    const float* __restrict__ x, const float* __restrict__ g,
    const float* __restrict__ b, unsigned short* __restrict__ y) {
    if (blockIdx.x < 6912) {
        __shared__ float tile[32][33];
        int tb = blockIdx.x;
        const float* src; unsigned short* dst; int K, N;
        if (tb < 2304) {
            K = 768; N = 768;
            int m = tb / 576; tb -= m * 576;
            src = (m == 0) ? q : (m == 1) ? k : (m == 2) ? v : o;
            dst = wT + (m < 3 ? (size_t)m * 589824 : (size_t)1769472);
        } else if (tb < 4608) {
            tb -= 2304; K = 768; N = 3072; src = w1; dst = wT + 2359296;
        } else {
            tb -= 4608; K = 3072; N = 768; src = w2; dst = wT + 4718592;
        }
        int TN = N >> 5;
        int tn = tb % TN, tk = tb / TN;
        int t = threadIdx.x, r = t >> 3, c4 = (t & 7) << 2;
        float4 vv = *reinterpret_cast<const float4*>(
            &src[(size_t)(tk * 32 + r) * N + tn * 32 + c4]);
        tile[r][c4 + 0] = vv.x; tile[r][c4 + 1] = vv.y;
        tile[r][c4 + 2] = vv.z; tile[r][c4 + 3] = vv.w;
        __syncthreads();
        us4 ov = { f2bf(tile[c4 + 0][r]), f2bf(tile[c4 + 1][r]),
                   f2bf(tile[c4 + 2][r]), f2bf(tile[c4 + 3][r]) };
        *reinterpret_cast<us4*>(&dst[(size_t)(tn * 32 + r) * K + tk * 32 + c4]) = ov;
    } else {
        __shared__ float red[8];
        int row = blockIdx.x - 6912, t = threadIdx.x;
        const float* xr = x + (size_t)row * DIM;
        float v0 = xr[t], v1 = xr[t + 256], v2 = xr[t + 512];
        float s = v0 + v1 + v2, sq = v0 * v0 + v1 * v1 + v2 * v2;
#pragma unroll
        for (int off = 1; off < 64; off <<= 1) {
            s += __shfl_xor(s, off);
            sq += __shfl_xor(sq, off);
        }
        if ((t & 63) == 0) { red[t >> 6] = s; red[4 + (t >> 6)] = sq; }
        __syncthreads();
        s = red[0] + red[1] + red[2] + red[3];
        sq = red[4] + red[5] + red[6] + red[7];
        float mu = s * (1.f / 768.f);
        float var = fmaxf(sq * (1.f / 768.f) - mu * mu, 0.f);
        float rs = rsqrtf(var + 1e-5f);
        unsigned short* yr = y + (size_t)row * DIM;
        yr[t]       = f2bf((v0 - mu) * rs * g[t] + b[t]);
        yr[t + 256] = f2bf((v1 - mu) * rs * g[t + 256] + b[t + 256]);
        yr[t + 512] = f2bf((v2 - mu) * rs * g[t + 512] + b[t + 512]);
    }
}

// pack per-layer qkv bias: bqkv[12][2304]
__global__ __launch_bounds__(256) void pack_bias(const float* __restrict__ bq,
                                                 const float* __restrict__ bk,
                                                 const float* __restrict__ bv,
                                                 float* __restrict__ dst) {
    int i = blockIdx.x * 256 + threadIdx.x;
    if (i >= 12 * QKVD) return;
    int l = i / QKVD, c = i % QKVD;
    float v = (c < 768) ? bq[l * 768 + c]
            : (c < 1536) ? bk[l * 768 + c - 768]
                         : bv[l * 768 + c - 1536];
    dst[i] = v;
}

// ================= 8-phase 256x256 GEMM (qkv only; round-6 race-fixed) ======
#define MM1(MF, J, NF) \
    acc[MF][NF] = MFMA16(af[J][0], bfr[NF][0], acc[MF][NF]); \
    acc[MF][NF] = MFMA16(af[J][1], bfr[NF][1], acc[MF][NF]);
#define MMROW(MF, J) MM1(MF, J, 0) MM1(MF, J, 1) MM1(MF, J, 2) MM1(MF, J, 3)

#define WAITVM(N) \
    __builtin_amdgcn_sched_barrier(0); \
    asm volatile("s_waitcnt vmcnt(" #N ")" ::: "memory"); \
    __builtin_amdgcn_sched_barrier(0);

template <int MODE>   // 0: bf16 out, 2: gelu->bf16
__global__ __launch_bounds__(512, 2) void gemm8p(
    const unsigned short* __restrict__ A, const unsigned short* __restrict__ Bt,
    const float* __restrict__ bias, int N, int K,
    unsigned short* __restrict__ outb) {
    __shared__ unsigned short Ab[2][16384];   // [dbuf][256*64]
    __shared__ unsigned short Bb[2][16384];
    const int tid = threadIdx.x, lane = tid & 63, wid = tid >> 6;
    const int wm = wid >> 2, wn = wid & 3;
    const int lr = lane & 15, lg = lane >> 4;
    const int ric = lane >> 3, sswz = (lane & 7) ^ ric;
    const int row0 = blockIdx.x * 256, col0 = blockIdx.y * 256;
    const char* pA = (const char*)A + ((size_t)(row0 + wid * 8 + ric) * K) * 2 + sswz * 16;
    const char* pB = (const char*)Bt + ((size_t)(col0 + wid * 8 + ric) * K) * 2 + sswz * 16;
    const int NT = K >> 6;

    auto stA = [&](int q, int ks, int b) {
        gload16(pA + ((size_t)q * 64 * K + ks) * 2, (char*)&Ab[b][0] + q * 8192 + wid * 1024);
    };
    auto stB = [&](int q, int ks, int b) {
        gload16(pB + ((size_t)q * 64 * K + ks) * 2, (char*)&Bb[b][0] + q * 8192 + wid * 1024);
    };

    f32x4 acc[8][4];
#pragma unroll
    for (int m = 0; m < 8; ++m)
#pragma unroll
        for (int n = 0; n < 4; ++n) acc[m][n] = (f32x4){0.f, 0.f, 0.f, 0.f};

    stB(0, 0, 0); stB(1, 0, 0); stB(2, 0, 0); stB(3, 0, 0);
    stA(0, 0, 0); stA(2, 0, 0); stA(1, 0, 0); stA(3, 0, 0);
    if (NT > 1) {
        stB(0, 64, 1); stB(1, 64, 1); stB(2, 64, 1); stB(3, 64, 1);
        stA(0, 64, 1); stA(2, 64, 1);
        WAITVM(4)
    } else {
        WAITVM(0)
    }
    __builtin_amdgcn_s_barrier();

    const int rsw = lr & 7;
    for (int s = 0; s < NT; ++s) {
        const int d = s & 1;
        const unsigned short* Ad = &Ab[d][0];
        const unsigned short* Bd = &Bb[d][0];
        const bool p1ok = (s + 1 < NT), p2ok = (s + 2 < NT);
        short8 bfr[4][2], af[2][2];
        // -------- phase 0
#pragma unroll
        for (int nf = 0; nf < 4; ++nf)
#pragma unroll
            for (int kk = 0; kk < 2; ++kk)
                bfr[nf][kk] = *reinterpret_cast<const short8*>(
                    &Bd[(wn * 64 + nf * 16 + lr) * 64 + (((kk * 4 + lg) ^ rsw) << 3)]);
#pragma unroll
        for (int j = 0; j < 2; ++j)
#pragma unroll
            for (int kk = 0; kk < 2; ++kk)
                af[j][kk] = *reinterpret_cast<const short8*>(
                    &Ad[(wm * 128 + (0 + j) * 16 + lr) * 64 + (((kk * 4 + lg) ^ rsw) << 3)]);
        if (p1ok) { stA(1, (s + 1) * 64, d ^ 1); stA(3, (s + 1) * 64, d ^ 1); }
        __builtin_amdgcn_s_barrier();
        __builtin_amdgcn_s_setprio(1);
        MMROW(0, 0) MMROW(1, 1)
        __builtin_amdgcn_s_setprio(0);
        __builtin_amdgcn_s_barrier();
        // -------- phase 1
#pragma unroll
        for (int j = 0; j < 2; ++j)
#pragma unroll
            for (int kk = 0; kk < 2; ++kk)
                af[j][kk] = *reinterpret_cast<const short8*>(
                    &Ad[(wm * 128 + (2 + j) * 16 + lr) * 64 + (((kk * 4 + lg) ^ rsw) << 3)]);
        if (p2ok) { stB(0, (s + 2) * 64, d); stB(1, (s + 2) * 64, d); }
        __builtin_amdgcn_s_barrier();
        __builtin_amdgcn_s_setprio(1);
        MMROW(2, 0) MMROW(3, 1)
        __builtin_amdgcn_s_setprio(0);
        __builtin_amdgcn_s_barrier();
        // -------- phase 2
#pragma unroll
        for (int j = 0; j < 2; ++j)
#pragma unroll
            for (int kk = 0; kk < 2; ++kk)
                af[j][kk] = *reinterpret_cast<const short8*>(
                    &Ad[(wm * 128 + (4 + j) * 16 + lr) * 64 + (((kk * 4 + lg) ^ rsw) << 3)]);
        if (p2ok) { stB(2, (s + 2) * 64, d); stB(3, (s + 2) * 64, d); }
        __builtin_amdgcn_s_barrier();
        __builtin_amdgcn_s_setprio(1);
        MMROW(4, 0) MMROW(5, 1)
        __builtin_amdgcn_s_setprio(0);
        __builtin_amdgcn_s_barrier();
        // -------- phase 3
#pragma unroll
        for (int j = 0; j < 2; ++j)
#pragma unroll
            for (int kk = 0; kk < 2; ++kk)
                af[j][kk] = *reinterpret_cast<const short8*>(
                    &Ad[(wm * 128 + (6 + j) * 16 + lr) * 64 + (((kk * 4 + lg) ^ rsw) << 3)]);
        if (p2ok) {
            stA(0, (s + 2) * 64, d); stA(2, (s + 2) * 64, d);
            WAITVM(4)
        } else {
            WAITVM(0)
        }
        __builtin_amdgcn_s_barrier();
        __builtin_amdgcn_s_setprio(1);
        MMROW(6, 0) MMROW(7, 1)
        __builtin_amdgcn_s_setprio(0);
        __builtin_amdgcn_s_barrier();
    }
#pragma unroll
    for (int m = 0; m < 8; ++m) {
#pragma unroll
        for (int n = 0; n < 4; ++n) {
            int gcol = col0 + wn * 64 + n * 16 + lr;
            float bv = bias[gcol];
#pragma unroll
            for (int i = 0; i < 4; ++i) {
                int grow = row0 + wm * 128 + m * 16 + lg * 4 + i;
                float v = acc[m][n][i] + bv;
                if (MODE == 2) v = 0.5f * v * (1.f + erff(v * 0.70710678118654752f));
                outb[(size_t)grow * N + gcol] = f2bf(v);
            }
        }
    }
}

// ---------------- round-3 2-barrier GEMM (proven best for short-K grids)
// mode 0: bf16 out  1: outf += (residual)  2: gelu->bf16  3: patch embed(+pos)
// mode 4: head fp32 out guarded to [32,NCLS], bias via pos ptr
template <int BM>
__global__ __launch_bounds__(256) void gemm_tn(
    const unsigned short* __restrict__ A, const unsigned short* __restrict__ Bt,
    const float* __restrict__ bias, int M, int N, int K, int mode,
    unsigned short* __restrict__ outb, float* __restrict__ outf,
    const float* __restrict__ pos) {
    constexpr int MFRAG = BM / 32;
    constexpr int ACH = BM / 8;
    constexpr int TOT = ACH + 16;
    constexpr int CPW = TOT / 4;
    __shared__ unsigned short Alds[BM * 64];
    __shared__ unsigned short Blds[128 * 64];
    const int tid = threadIdx.x, lane = tid & 63, wid = tid >> 6;
    const int row0 = blockIdx.x * BM, col0 = blockIdx.y * 128;
    const int wm = (wid >> 1) * (BM / 2), wn = (wid & 1) * 64;
    const int lr = lane & 15, lg = lane >> 4;
    const int ric = lane >> 3;
    const int sswz = (lane & 7) ^ ric;

    const char* gptr[CPW];
    char* lptr[CPW];
#pragma unroll
    for (int j = 0; j < CPW; ++j) {
        int cc = wid * CPW + j;
        if (cc < ACH) {
            int grow = row0 + cc * 8 + ric;
            gptr[j] = (const char*)A + (size_t)grow * K * 2 + sswz * 16;
            lptr[j] = (char*)Alds + cc * 1024;
        } else {
            int grow = col0 + (cc - ACH) * 8 + ric;
            gptr[j] = (const char*)Bt + (size_t)grow * K * 2 + sswz * 16;
            lptr[j] = (char*)Blds + (cc - ACH) * 1024;
        }
    }

    f32x4 acc[MFRAG][4];
#pragma unroll
    for (int m = 0; m < MFRAG; ++m)
#pragma unroll
        for (int n = 0; n < 4; ++n) acc[m][n] = (f32x4){0.f, 0.f, 0.f, 0.f};

    const int rsw = lr & 7;
    for (int ks = 0; ks < K; ks += 64) {
        __syncthreads();
#pragma unroll
        for (int j = 0; j < CPW; ++j) {
            gload16(gptr[j], lptr[j]);
            gptr[j] += 128;
        }
        __syncthreads();
        short8 af[MFRAG][2], bfr[4][2];
#pragma unroll
        for (int m = 0; m < MFRAG; ++m)
#pragma unroll
            for (int kk = 0; kk < 2; ++kk)
                af[m][kk] = *reinterpret_cast<const short8*>(
                    &Alds[(wm + m * 16 + lr) * 64 + (((kk * 4 + lg) ^ rsw) << 3)]);
#pragma unroll
        for (int n = 0; n < 4; ++n)
#pragma unroll
            for (int kk = 0; kk < 2; ++kk)
                bfr[n][kk] = *reinterpret_cast<const short8*>(
                    &Blds[(wn + n * 16 + lr) * 64 + (((kk * 4 + lg) ^ rsw) << 3)]);
#pragma unroll
        for (int m = 0; m < MFRAG; ++m)
#pragma unroll
            for (int n = 0; n < 4; ++n) {
                acc[m][n] = MFMA16(af[m][0], bfr[n][0], acc[m][n]);
                acc[m][n] = MFMA16(af[m][1], bfr[n][1], acc[m][n]);
            }
    }
#pragma unroll
    for (int m = 0; m < MFRAG; ++m) {
#pragma unroll
        for (int n = 0; n < 4; ++n) {
            int gcol = col0 + wn + n * 16 + lr;
            float bv = bias ? bias[gcol] : 0.f;
#pragma unroll
            for (int i = 0; i < 4; ++i) {
                int grow = row0 + wm + m * 16 + lg * 4 + i;
                float v = acc[m][n][i] + bv;
                if (mode == 0) {
                    outb[(size_t)grow * N + gcol] = f2bf(v);
                } else if (mode == 1) {
                    outf[(size_t)grow * N + gcol] += v;
                } else if (mode == 2) {
                    v = 0.5f * v * (1.f + erff(v * 0.70710678118654752f));
                    outb[(size_t)grow * N + gcol] = f2bf(v);
                } else if (mode == 3) {
                    int pb = grow / NPATCH, pn = grow % NPATCH;
                    size_t o = ((size_t)pb * SPAD + 1 + pn) * DIM + gcol;
                    outf[o] = v + pos[(size_t)(1 + pn) * DIM + gcol];
                } else {
                    if (grow < BATCH && gcol < NCLS)
                        outf[(size_t)grow * NCLS + gcol] = v + pos[gcol];
                }
            }
        }
    }
}

// ---------------- LayerNorm fp32 -> bf16, one block per row (D=768)
__global__ __launch_bounds__(256) void ln_bf16(const float* __restrict__ x,
                                               const float* __restrict__ g,
                                               const float* __restrict__ b,
                                               unsigned short* __restrict__ y) {
    __shared__ float red[8];
    int row = blockIdx.x, t = threadIdx.x;
    const float* xr = x + (size_t)row * DIM;
    float v0 = xr[t], v1 = xr[t + 256], v2 = xr[t + 512];
    float s = v0 + v1 + v2, sq = v0 * v0 + v1 * v1 + v2 * v2;
#pragma unroll
    for (int off = 1; off < 64; off <<= 1) {
        s += __shfl_xor(s, off);
        sq += __shfl_xor(sq, off);
    }
    if ((t & 63) == 0) { red[t >> 6] = s; red[4 + (t >> 6)] = sq; }
    __syncthreads();
    s = red[0] + red[1] + red[2] + red[3];
    sq = red[4] + red[5] + red[6] + red[7];
    float mu = s * (1.f / 768.f);
    float var = fmaxf(sq * (1.f / 768.f) - mu * mu, 0.f);
    float rs = rsqrtf(var + 1e-5f);
    unsigned short* yr = y + (size_t)row * DIM;
    yr[t]       = f2bf((v0 - mu) * rs * g[t] + b[t]);
    yr[t + 256] = f2bf((v1 - mu) * rs * g[t + 256] + b[t + 256]);
    yr[t + 512] = f2bf((v2 - mu) * rs * g[t + 512] + b[t + 512]);
}

// LN of cls rows only -> clsbuf bf16 [64][768] (rows 32..63 zero)
__global__ __launch_bounds__(256) void ln_cls(const float* __restrict__ x,
                                              const float* __restrict__ g,
                                              const float* __restrict__ b,
                                              unsigned short* __restrict__ y) {
    __shared__ float red[8];
    int bb = blockIdx.x, t = threadIdx.x;
    unsigned short* yr = y + (size_t)bb * DIM;
    if (bb >= BATCH) {
        yr[t] = 0; yr[t + 256] = 0; yr[t + 512] = 0;
        return;
    }
    const float* xr = x + (size_t)bb * SPAD * DIM;
    float v0 = xr[t], v1 = xr[t + 256], v2 = xr[t + 512];
    float s = v0 + v1 + v2, sq = v0 * v0 + v1 * v1 + v2 * v2;
#pragma unroll
    for (int off = 1; off < 64; off <<= 1) {
        s += __shfl_xor(s, off);
        sq += __shfl_xor(sq, off);
    }
    if ((t & 63) == 0) { red[t >> 6] = s; red[4 + (t >> 6)] = sq; }
    __syncthreads();
    s = red[0] + red[1] + red[2] + red[3];
    sq = red[4] + red[5] + red[6] + red[7];
    float mu = s * (1.f / 768.f);
    float var = fmaxf(sq * (1.f / 768.f) - mu * mu, 0.f);
    float rs = rsqrtf(var + 1e-5f);
    yr[t]       = f2bf((v0 - mu) * rs * g[t] + b[t]);
    yr[t + 256] = f2bf((v1 - mu) * rs * g[t + 256] + b[t + 256]);
    yr[t + 512] = f2bf((v2 - mu) * rs * g[t + 512] + b[t + 512]);
}

// ---------------- fused attention: per (h,b) block, 8 waves (512 thr).
// Per-wave algorithm identical to round-6 (proven); staging/qt stride 8.
// LDS 121KB -> 1 block/CU with 8 waves (vs 4) for latency hiding.
__global__ __launch_bounds__(512) void attn_fused(const unsigned short* __restrict__ qkv,
                                                  unsigned short* __restrict__ att) {
    __shared__ unsigned short Klds[26 * 512];
    __shared__ unsigned short Vlds[64][232];
    __shared__ unsigned short Plds[8][16 * 256];
    int h = blockIdx.x, b = blockIdx.y, tid = threadIdx.x;
    int wid = tid >> 6, lane = tid & 63, lr = lane & 15, lg = lane >> 4;
    const int ric = lane >> 3, sswz = (lane & 7) ^ ric;

    const char* pK = (const char*)qkv +
        ((size_t)(b * SPAD + ric) * QKVD + 768 + h * DKH) * 2 + sswz * 16;
    for (int c = wid; c < 26; c += 8)
        gload16(pK + (size_t)c * 8 * QKVD * 2, (char*)Klds + c * 1024);

    for (int idx = tid; idx < SPAD * 8; idx += 512) {
        int s = idx >> 3, dc = (idx & 7) << 3;
        uint4 w = *reinterpret_cast<const uint4*>(
            &qkv[((size_t)b * SPAD + s) * QKVD + 1536 + h * DKH + dc]);
        const unsigned short* pe = reinterpret_cast<const unsigned short*>(&w);
#pragma unroll
        for (int i = 0; i < 8; ++i) Vlds[dc + i][s] = pe[i];
    }
    for (int i = tid; i < 64 * 24; i += 512) Vlds[i / 24][208 + (i % 24)] = 0;
    __syncthreads();

    unsigned short* Pw = &Plds[wid][0];
    const short8 zero8 = {0, 0, 0, 0, 0, 0, 0, 0};
    const int rowin = lr & 7;

    for (int qt = wid; qt < 13; qt += 8) {
        size_t qoff = ((size_t)b * SPAD + qt * 16 + lr) * QKVD + h * DKH + lg * 8;
        short8 qf0 = *reinterpret_cast<const short8*>(&qkv[qoff]);
        short8 qf1 = *reinterpret_cast<const short8*>(&qkv[qoff + 32]);
        f32x4 acc[13];
#pragma unroll
        for (int kt = 0; kt < 13; ++kt) {
            const unsigned short* kbase = Klds + (kt * 2 + (lr >> 3)) * 512 + rowin * 64;
            short8 kf0 = *reinterpret_cast<const short8*>(&kbase[(lg ^ rowin) << 3]);
            short8 kf1 = *reinterpret_cast<const short8*>(&kbase[((4 + lg) ^ rowin) << 3]);
            f32x4 a = (f32x4){0.f, 0.f, 0.f, 0.f};
            a = MFMA16(qf0, kf0, a);
            a = MFMA16(qf1, kf1, a);
            acc[kt] = a;
        }
#pragma unroll
        for (int kt = 0; kt < 13; ++kt)
#pragma unroll
            for (int r = 0; r < 4; ++r) acc[kt][r] *= 0.125f;
        if (lr >= 5) {
#pragma unroll
            for (int r = 0; r < 4; ++r) acc[12][r] = -1e30f;   // tokens >=197
        }
        float mx[4] = {-1e30f, -1e30f, -1e30f, -1e30f};
#pragma unroll
        for (int kt = 0; kt < 13; ++kt)
#pragma unroll
            for (int r = 0; r < 4; ++r) mx[r] = fmaxf(mx[r], acc[kt][r]);
#pragma unroll
        for (int r = 0; r < 4; ++r) {
            mx[r] = fmaxf(mx[r], __shfl_xor(mx[r], 1));
            mx[r] = fmaxf(mx[r], __shfl_xor(mx[r], 2));
            mx[r] = fmaxf(mx[r], __shfl_xor(mx[r], 4));
            mx[r] = fmaxf(mx[r], __shfl_xor(mx[r], 8));
        }
        float sm[4] = {0.f, 0.f, 0.f, 0.f};
#pragma unroll
        for (int kt = 0; kt < 13; ++kt)
#pragma unroll
            for (int r = 0; r < 4; ++r) {
                float e = __expf(acc[kt][r] - mx[r]);
                acc[kt][r] = e;
                sm[r] += e;
            }
#pragma unroll
        for (int r = 0; r < 4; ++r) {
            sm[r] += __shfl_xor(sm[r], 1);
            sm[r] += __shfl_xor(sm[r], 2);
            sm[r] += __shfl_xor(sm[r], 4);
            sm[r] += __shfl_xor(sm[r], 8);
        }
#pragma unroll
        for (int r = 0; r < 4; ++r) {
            int row = lg * 4 + r;
            float inv = 1.f / sm[r];
#pragma unroll
            for (int kt = 0; kt < 13; ++kt) {
                int col = kt * 16 + lr;
                int idx = row * 256 + ((((col >> 3) ^ (row & 7)) << 3) | (col & 7));
                Pw[idx] = f2bf(acc[kt][r] * inv);
            }
        }
        if (lr < 6) {
            int s = 26 + lr;
#pragma unroll
            for (int r = 0; r < 4; ++r) {
                int row = lg * 4 + r;
                *reinterpret_cast<short8*>(&Pw[row * 256 + ((s ^ (row & 7)) << 3)]) = zero8;
            }
        }
        int rsw = lr & 7;
#pragma unroll
        for (int dt = 0; dt < 4; ++dt) {
            f32x4 a = (f32x4){0.f, 0.f, 0.f, 0.f};
#pragma unroll
            for (int kk = 0; kk < 7; ++kk) {
                short8 af = *reinterpret_cast<const short8*>(
                    &Pw[lr * 256 + (((kk * 4 + lg) ^ rsw) << 3)]);
                short8 bfr = *reinterpret_cast<const short8*>(
                    &Vlds[dt * 16 + lr][kk * 32 + lg * 8]);
                a = MFMA16(af, bfr, a);
            }
#pragma unroll
            for (int i = 0; i < 4; ++i) {
                int s = qt * 16 + lg * 4 + i;
                att[((size_t)b * SPAD + s) * DIM + h * DKH + dt * 16 + lr] = f2bf(a[i]);
            }
        }
    }
}

extern "C" void kernel_launch(void* const* d_in, const int* in_sizes, int n_in,
                              void* d_out, int out_size, void* d_ws, size_t ws_size,
                              hipStream_t stream) {
    const float* x      = (const float*)d_in[0];
    const float* patchW = (const float*)d_in[1];
    const float* patchB = (const float*)d_in[2];
    const float* clstok = (const float*)d_in[3];
    const float* pose   = (const float*)d_in[4];
    const float* Wq = (const float*)d_in[5];
    const float* bq = (const float*)d_in[6];
    const float* Wk = (const float*)d_in[7];
    const float* bk = (const float*)d_in[8];
    const float* Wv = (const float*)d_in[9];
    const float* bv = (const float*)d_in[10];
    const float* Wo = (const float*)d_in[11];
    const float* bo = (const float*)d_in[12];
    const float* ln1g = (const float*)d_in[13];
    const float* ln1b = (const float*)d_in[14];
    const float* ln2g = (const float*)d_in[15];
    const float* ln2b = (const float*)d_in[16];
    const float* W1 = (const float*)d_in[17];
    const float* b1 = (const float*)d_in[18];
    const float* W2 = (const float*)d_in[19];
    const float* b2 = (const float*)d_in[20];
    const float* lnpg = (const float*)d_in[21];
    const float* lnpb = (const float*)d_in[22];
    const float* headW = (const float*)d_in[23];
    const float* headB = (const float*)d_in[24];
    float* out = (float*)d_out;

    // ws footprint ~117MB -> working set stays L3-resident (round-9 lesson).
    constexpr size_t SZ_H   = (size_t)ROWS * DIM * 4;
    constexpr size_t SZ_QKV = (size_t)ROWS * QKVD * 2;
    constexpr size_t SZ_Y   = (size_t)ROWS * DIM * 2;
    constexpr size_t SZ_M1  = (size_t)ROWS * MLPD * 2;
    constexpr size_t SZ_WT  = (size_t)WT_ELEMS * 2;
    char* w = (char*)d_ws;
    float* hbuf            = (float*)w;
    unsigned short* qkvb   = (unsigned short*)(w + SZ_H);
    unsigned short* ybuf   = (unsigned short*)(w + SZ_H + SZ_QKV);
    unsigned short* m1buf  = (unsigned short*)(w + SZ_H + SZ_QKV + SZ_Y);
    unsigned short* wT     = (unsigned short*)(w + SZ_H + SZ_QKV + SZ_Y + SZ_M1);
    float* bqkv            = (float*)(w + SZ_H + SZ_QKV + SZ_Y + SZ_M1 + SZ_WT);
    unsigned short* patches = m1buf;          // embed phase (4.8M elems @ m1buf)
    unsigned short* pwT     = ybuf;           // patch weightT scratch (ybuf idle
                                              // until layer-0 LN)
    unsigned short* clsbuf  = m1buf;          // head phase [64][768]
    unsigned short* hwT     = m1buf + 64 * DIM;  // head phase [1024][768]

    pack_bias<<<dim3(108), 256, 0, stream>>>(bq, bk, bv, bqkv);

    // patch embed (patches in m1buf, weightsT in ybuf — disjoint)
    tconv<<<dim3(24, 24), 256, 0, stream>>>(patchW, pwT, PDIM, DIM);
    patchify<<<dim3((BATCH * NPATCH * PDIM + 255) / 256), 256, 0, stream>>>(x, patches);
    embed_misc<<<dim3(BATCH), 256, 0, stream>>>(clstok, pose, hbuf);
    gemm_tn<64><<<dim3(98, 6), 256, 0, stream>>>(patches, pwT, patchB,
                                                 BATCH * NPATCH, DIM, PDIM, 3,
                                                 nullptr, hbuf, pose);

    for (int i = 0; i < 12; ++i) {
        // fused: weight conversion (blocks 0..6911) + LN1 (blocks 6912..13567)
        ln_wconv<<<dim3(6912 + ROWS), 256, 0, stream>>>(
            Wq + (size_t)i * DIM * DIM, Wk + (size_t)i * DIM * DIM,
            Wv + (size_t)i * DIM * DIM, Wo + (size_t)i * DIM * DIM,
            W1 + (size_t)i * DIM * MLPD, W2 + (size_t)i * DIM * MLPD, wT,
            hbuf, ln1g + i * DIM, ln1b + i * DIM, ybuf);
        gemm8p<0><<<dim3(26, 9), 512, 0, stream>>>(ybuf, wT, bqkv + i * QKVD,
                                                   QKVD, DIM, qkvb);
        attn_fused<<<dim3(HEADS, BATCH), 512, 0, stream>>>(qkvb, ybuf);
        gemm_tn<64><<<dim3(104, 6), 256, 0, stream>>>(ybuf, wT + 1769472, bo + i * DIM,
                                                      ROWS, DIM, DIM, 1,
                                                      nullptr, hbuf, nullptr);
        ln_bf16<<<dim3(ROWS), 256, 0, stream>>>(hbuf, ln2g + i * DIM, ln2b + i * DIM, ybuf);
        gemm_tn<128><<<dim3(52, 24), 256, 0, stream>>>(ybuf, wT + 2359296, b1 + i * MLPD,
                                                       ROWS, MLPD, DIM, 2,
                                                       m1buf, nullptr, nullptr);
        gemm_tn<64><<<dim3(104, 6), 256, 0, stream>>>(m1buf, wT + 4718592, b2 + i * DIM,
                                                      ROWS, DIM, MLPD, 1,
                                                      nullptr, hbuf, nullptr);
    }
    // head: LN cls rows -> clsbuf [64][768]; headW -> hwT [1024][768]; MFMA GEMM
    ln_cls<<<dim3(64), 256, 0, stream>>>(hbuf, lnpg, lnpb, clsbuf);
    hconv<<<dim3(32, 24), 256, 0, stream>>>(headW, hwT);
    gemm_tn<64><<<dim3(1, 8), 256, 0, stream>>>(clsbuf, hwT, nullptr,
                                                64, 1024, DIM, 4,
                                                nullptr, out, headB);
}